// Round 11
// baseline (178.547 us; speedup 1.0000x reference)
//
#include <hip/hip_runtime.h>
#include <hip/hip_fp16.h>
#include <math.h>

#define F_IN   256
#define C1     128   // H1*D1
#define H1N    4
#define D2N    64

#define SCAN_T    256
#define SCAN_TILE 512   // 2 elements per thread

#define BK1 32          // gemm K-tile

// ---------------- utility ----------------
__global__ void zero_ints(int* p, int n) {
    int i = blockIdx.x * blockDim.x + threadIdx.x;
    for (; i < n; i += gridDim.x * blockDim.x) p[i] = 0;
}

// ---------------- fused: layer-1 GEMM (blocks < ngemm) + edge count/rank (rest) ----------------
// GEMM: BM=64, BN=128, BK=32; 128 threads; 8x8 acc/thread in split layout:
// rows {ty*4..+3, 32+ty*4..+3}, cols {tx*4..+3, 64+tx*4..+3}  (2-way-max LDS aliasing = free)
__global__ __launch_bounds__(128) void gemm1_count_kernel(
        const float* __restrict__ x, const float* __restrict__ W1,
        const float* __restrict__ attS, const float* __restrict__ attD,
        __half* __restrict__ hx1h, float* __restrict__ as1, float* __restrict__ ad1,
        int N,
        const int* __restrict__ dst, int* __restrict__ counts,
        int* __restrict__ edge_rank, int E, int ngemm) {
    if ((int)blockIdx.x >= ngemm) {
        int b  = blockIdx.x - ngemm;
        int nb = gridDim.x - ngemm;
        for (int i = b * blockDim.x + threadIdx.x; i < E; i += nb * blockDim.x)
            edge_rank[i] = atomicAdd(&counts[dst[i]], 1);
        return;
    }

    __shared__ float xT[BK1][64 + 4];   // transposed x tile
    __shared__ float ws[BK1][C1];

    int tid = threadIdx.x;
    int tx  = tid & 15;          // col groups: tx*4.. and 64+tx*4..
    int ty  = tid >> 4;          // row groups: ty*4.. and 32+ty*4..   (0..7)
    int n0  = blockIdx.x * 64;

    float acc[8][8];             // [row: 0-3 lo,4-7 hi][col: 0-3 lo,4-7 hi]
#pragma unroll
    for (int r = 0; r < 8; ++r)
#pragma unroll
        for (int c = 0; c < 8; ++c) acc[r][c] = 0.f;

    // staging assignments
    int lr8 = tid >> 3;                // 0..15 (x row within 16-row pass)
    int lk8 = (tid & 7) * 4;           // 0..28 (x k offset)
    int kw  = tid >> 5;                // 0..3  (w k row within 4-row pass)
    int cw  = (tid & 31) * 4;          // 0..124

    for (int k0 = 0; k0 < F_IN; k0 += BK1) {
        float4 xv[4], wv[8];
#pragma unroll
        for (int p = 0; p < 4; ++p) {
            int row = n0 + p * 16 + lr8; if (row >= N) row = N - 1;
            xv[p] = *(const float4*)(x + (size_t)row * F_IN + k0 + lk8);
        }
#pragma unroll
        for (int p = 0; p < 8; ++p)
            wv[p] = *(const float4*)(W1 + (size_t)(k0 + p * 4 + kw) * C1 + cw);
        __syncthreads();               // previous tile fully consumed
#pragma unroll
        for (int p = 0; p < 4; ++p) {
            int row = p * 16 + lr8;
            xT[lk8 + 0][row] = xv[p].x; xT[lk8 + 1][row] = xv[p].y;
            xT[lk8 + 2][row] = xv[p].z; xT[lk8 + 3][row] = xv[p].w;
        }
#pragma unroll
        for (int p = 0; p < 8; ++p)
            *(float4*)&ws[p * 4 + kw][cw] = wv[p];
        __syncthreads();
#pragma unroll
        for (int k = 0; k < BK1; ++k) {
            float4 xa = *(const float4*)&xT[k][ty * 4];        // broadcast in 16-lane groups
            float4 xb = *(const float4*)&xT[k][32 + ty * 4];
            float4 wa = *(const float4*)&ws[k][tx * 4];        // 2-way aliasing (free)
            float4 wb = *(const float4*)&ws[k][64 + tx * 4];
            float xr[8] = {xa.x, xa.y, xa.z, xa.w, xb.x, xb.y, xb.z, xb.w};
            float wc[8] = {wa.x, wa.y, wa.z, wa.w, wb.x, wb.y, wb.z, wb.w};
#pragma unroll
            for (int r = 0; r < 8; ++r)
#pragma unroll
                for (int c = 0; c < 8; ++c) acc[r][c] += xr[r] * wc[c];
        }
    }

    // epilogue: attention logits + fp16 store
    const float4 asA = *(const float4*)(attS + tx * 4);
    const float4 asB = *(const float4*)(attS + 64 + tx * 4);
    const float4 adA = *(const float4*)(attD + tx * 4);
    const float4 adB = *(const float4*)(attD + 64 + tx * 4);
    int hA = tx >> 3;            // head of low col group (0/1)
    int hB = 2 + (tx >> 3);      // head of high col group (2/3)
#pragma unroll
    for (int r = 0; r < 8; ++r) {
        int n = n0 + ((r < 4) ? (ty * 4 + r) : (32 + ty * 4 + r - 4));
        float tsA = acc[r][0]*asA.x + acc[r][1]*asA.y + acc[r][2]*asA.z + acc[r][3]*asA.w;
        float tdA = acc[r][0]*adA.x + acc[r][1]*adA.y + acc[r][2]*adA.z + acc[r][3]*adA.w;
        float tsB = acc[r][4]*asB.x + acc[r][5]*asB.y + acc[r][6]*asB.z + acc[r][7]*asB.w;
        float tdB = acc[r][4]*adB.x + acc[r][5]*adB.y + acc[r][6]*adB.z + acc[r][7]*adB.w;
        // reduce across the 8 lanes (tx bits 0..2) sharing each head — unconditional
        tsA += __shfl_xor(tsA, 1); tdA += __shfl_xor(tdA, 1);
        tsB += __shfl_xor(tsB, 1); tdB += __shfl_xor(tdB, 1);
        tsA += __shfl_xor(tsA, 2); tdA += __shfl_xor(tdA, 2);
        tsB += __shfl_xor(tsB, 2); tdB += __shfl_xor(tdB, 2);
        tsA += __shfl_xor(tsA, 4); tdA += __shfl_xor(tdA, 4);
        tsB += __shfl_xor(tsB, 4); tdB += __shfl_xor(tdB, 4);
        if (n < N) {
            __half2* hp = (__half2*)&hx1h[(size_t)n * C1 + tx * 4];
            hp[0] = __floats2half2_rn(acc[r][0], acc[r][1]);
            hp[1] = __floats2half2_rn(acc[r][2], acc[r][3]);
            __half2* hq = (__half2*)&hx1h[(size_t)n * C1 + 64 + tx * 4];
            hq[0] = __floats2half2_rn(acc[r][4], acc[r][5]);
            hq[1] = __floats2half2_rn(acc[r][6], acc[r][7]);
            if ((tx & 7) == 0) {
                as1[n * H1N + hA] = tsA; ad1[n * H1N + hA] = tdA;
                as1[n * H1N + hB] = tsB; ad1[n * H1N + hB] = tdB;
            }
        }
    }
}

// ---------------- scan: counts -> offsets ----------------
__global__ void scan_partial(const int* __restrict__ counts, int* __restrict__ tilesums, int N) {
    __shared__ int red[SCAN_T];
    int t  = threadIdx.x;
    int i0 = blockIdx.x * SCAN_TILE + 2 * t;
    int s = 0;
    if (i0     < N) s += counts[i0];
    if (i0 + 1 < N) s += counts[i0 + 1];
    red[t] = s;
    __syncthreads();
    for (int off = SCAN_T / 2; off > 0; off >>= 1) {
        if (t < off) red[t] += red[t + off];
        __syncthreads();
    }
    if (t == 0) tilesums[blockIdx.x] = red[0];
}

__global__ void scan_tops(const int* __restrict__ tilesums, int* __restrict__ tilebase, int ntiles) {
    __shared__ int sh[SCAN_T];
    int t = threadIdx.x;
    int v = (t < ntiles) ? tilesums[t] : 0;
    sh[t] = v;
    __syncthreads();
    for (int off = 1; off < SCAN_T; off <<= 1) {
        int u = (t >= off) ? sh[t - off] : 0;
        __syncthreads();
        sh[t] += u;
        __syncthreads();
    }
    tilebase[t] = sh[t] - v;
}

__global__ void scan_final(const int* __restrict__ counts, const int* __restrict__ tilebase,
                           int* __restrict__ offsets, int N, int E) {
    __shared__ int sh[SCAN_T];
    int t  = threadIdx.x;
    int i0 = blockIdx.x * SCAN_TILE + 2 * t;
    int a   = (i0     < N) ? counts[i0]     : 0;
    int b   = (i0 + 1 < N) ? counts[i0 + 1] : 0;
    int tot = a + b;
    sh[t] = tot;
    __syncthreads();
    for (int off = 1; off < SCAN_T; off <<= 1) {
        int u = (t >= off) ? sh[t - off] : 0;
        __syncthreads();
        sh[t] += u;
        __syncthreads();
    }
    int excl = sh[t] - tot + tilebase[blockIdx.x];
    if (i0 < N)     offsets[i0]     = excl;
    if (i0 + 1 < N) offsets[i0 + 1] = excl + a;
    if (blockIdx.x == 0 && t == 0) offsets[N] = E;
}

// ---------------- atomic-free, XCD-binned scatter ----------------
__global__ void scatter_rank(const int* __restrict__ src, const int* __restrict__ dst,
                             const int* __restrict__ edge_rank, const int* __restrict__ offsets,
                             int* __restrict__ edge_src, int E, int N) {
    int grp  = blockIdx.x & 7;
    int gidx = blockIdx.x >> 3;
    int ngrp = gridDim.x >> 3;
    int lo = (int)((long long)N * grp / 8);
    int hi = (int)((long long)N * (grp + 1) / 8);
    for (int i = gidx * blockDim.x + threadIdx.x; i < E; i += ngrp * blockDim.x) {
        int d = dst[i];
        if (d >= lo && d < hi)
            edge_src[offsets[d] + edge_rank[i]] = src[i];
    }
}

// ---------------- layer 1 aggregate: no-max softmax, fp16 gather ----------------
__global__ void agg1_kernel(const int* __restrict__ edge_src, const int* __restrict__ offsets,
                            const float* __restrict__ as1, const float* __restrict__ ad1,
                            const __half* __restrict__ hx1h, const float* __restrict__ b1,
                            float* __restrict__ x1, int N) {
    __shared__ int   ssh[4][64];
    __shared__ float esh[4][64][4];
    int wid  = threadIdx.x >> 6;
    int n    = (blockIdx.x * blockDim.x + threadIdx.x) >> 6;
    int lane = threadIdx.x & 63;
    if (n >= N) return;
    int hsel = lane >> 4;                    // head of cols (2l, 2l+1)
    const float4 ad4 = *(const float4*)(ad1 + 4 * n);
    int beg = offsets[n], end = offsets[n + 1];

    float den[4] = {0.f, 0.f, 0.f, 0.f};
    float acc0 = 0.f, acc1 = 0.f;

    for (int cb = beg; cb < end; cb += 64) {
        int j = cb + lane;
        bool valid = j < end;
        int s = valid ? edge_src[j] : 0;
        float e0 = 0.f, e1 = 0.f, e2 = 0.f, e3 = 0.f;
        if (valid) {
            const float4 a4 = *(const float4*)(as1 + 4 * s);
            float v0 = a4.x + ad4.x, v1 = a4.y + ad4.y;
            float v2 = a4.z + ad4.z, v3 = a4.w + ad4.w;
            v0 = v0 > 0.f ? v0 : 0.2f * v0;
            v1 = v1 > 0.f ? v1 : 0.2f * v1;
            v2 = v2 > 0.f ? v2 : 0.2f * v2;
            v3 = v3 > 0.f ? v3 : 0.2f * v3;
            e0 = __expf(v0); e1 = __expf(v1);
            e2 = __expf(v2); e3 = __expf(v3);
            den[0] += e0; den[1] += e1; den[2] += e2; den[3] += e3;
        }
        ssh[wid][lane] = s;
        *(float4*)&esh[wid][lane][0] = make_float4(e0, e1, e2, e3);

        int cnt = min(64, end - cb);
#pragma unroll 4
        for (int jj = 0; jj < cnt; ++jj) {
            int   sj = ssh[wid][jj];
            float w  = esh[wid][jj][hsel];
            const __half2* hr = (const __half2*)(hx1h + (size_t)sj * C1);
            float2 vf = __half22float2(hr[lane]);
            acc0 += w * vf.x;
            acc1 += w * vf.y;
        }
    }

#pragma unroll
    for (int off = 32; off > 0; off >>= 1)
#pragma unroll
        for (int h = 0; h < 4; ++h) den[h] += __shfl_xor(den[h], off, 64);

    float d = lane < 16 ? den[0] : lane < 32 ? den[1] : lane < 48 ? den[2] : den[3];
    float inv = 1.f / (d + 1e-16f);
    float2 bv = *(const float2*)(b1 + 2 * lane);
    float o0 = acc0 * inv + bv.x;
    float o1 = acc1 * inv + bv.y;
    o0 = o0 > 0.f ? o0 : (__expf(o0) - 1.f);   // ELU
    o1 = o1 > 0.f ? o1 : (__expf(o1) - 1.f);
    *(float2*)&x1[(size_t)n * C1 + 2 * lane] = make_float2(o0, o1);
}

// ---------------- layer 2 GEMM: hx2 = x1 @ W2 (+ logits), register-tiled ----------------
__global__ __launch_bounds__(256) void gemm2_kernel(
        const float* __restrict__ x1, const float* __restrict__ W2,
        const float* __restrict__ attS, const float* __restrict__ attD,
        float* __restrict__ hx2, float* __restrict__ as2, float* __restrict__ ad2,
        int N) {
    __shared__ float xT[BK1][64 + 4];
    __shared__ float ws2[BK1][D2N];

    int tid = threadIdx.x;
    int tx  = tid & 15;          // col group: cols tx*4 .. tx*4+3
    int ty  = tid >> 4;          // row group: rows ty*4 .. ty*4+3
    int n0  = blockIdx.x * 64;

    float acc[4][4];
#pragma unroll
    for (int r = 0; r < 4; ++r)
#pragma unroll
        for (int c = 0; c < 4; ++c) acc[r][c] = 0.f;

    int lr = tid >> 2;                 // 0..63
    int lk = (tid & 3) * 4;            // 0,4,8,12
    int xrow = n0 + lr; if (xrow >= N) xrow = N - 1;
    const float* xptr = x1 + (size_t)xrow * C1;
    int kw = tid >> 4;                 // 0..15
    int cw = tx * 4;

    for (int k0 = 0; k0 < C1; k0 += BK1) {
        float4 a0 = *(const float4*)(xptr + k0 + lk);
        float4 a1 = *(const float4*)(xptr + k0 + lk + 16);
        float4 w0 = *(const float4*)(W2 + (size_t)(k0 + kw     ) * D2N + cw);
        float4 w1 = *(const float4*)(W2 + (size_t)(k0 + kw + 16) * D2N + cw);
        __syncthreads();
        xT[lk + 0][lr] = a0.x; xT[lk + 1][lr] = a0.y;
        xT[lk + 2][lr] = a0.z; xT[lk + 3][lr] = a0.w;
        xT[lk + 16][lr] = a1.x; xT[lk + 17][lr] = a1.y;
        xT[lk + 18][lr] = a1.z; xT[lk + 19][lr] = a1.w;
        *(float4*)&ws2[kw     ][cw] = w0;
        *(float4*)&ws2[kw + 16][cw] = w1;
        __syncthreads();
#pragma unroll
        for (int k = 0; k < BK1; ++k) {
            float4 xa = *(const float4*)&xT[k][ty * 4];
            float4 wv = *(const float4*)&ws2[k][tx * 4];
            float xr[4] = {xa.x, xa.y, xa.z, xa.w};
            float wc[4] = {wv.x, wv.y, wv.z, wv.w};
#pragma unroll
            for (int r = 0; r < 4; ++r)
#pragma unroll
                for (int c = 0; c < 4; ++c) acc[r][c] += xr[r] * wc[c];
        }
    }

    const float4 asv = *(const float4*)(attS + tx * 4);
    const float4 adv = *(const float4*)(attD + tx * 4);
#pragma unroll
    for (int r = 0; r < 4; ++r) {
        int n = n0 + ty * 4 + r;
        float ts = acc[r][0] * asv.x + acc[r][1] * asv.y + acc[r][2] * asv.z + acc[r][3] * asv.w;
        float td = acc[r][0] * adv.x + acc[r][1] * adv.y + acc[r][2] * adv.z + acc[r][3] * adv.w;
        ts += __shfl_xor(ts, 1); td += __shfl_xor(td, 1);
        ts += __shfl_xor(ts, 2); td += __shfl_xor(td, 2);
        ts += __shfl_xor(ts, 4); td += __shfl_xor(td, 4);
        ts += __shfl_xor(ts, 8); td += __shfl_xor(td, 8);
        if (n < N) {
            *(float4*)&hx2[(size_t)n * D2N + tx * 4] =
                make_float4(acc[r][0], acc[r][1], acc[r][2], acc[r][3]);
            if (tx == 0) { as2[n] = ts; ad2[n] = td; }
        }
    }
}

// ---------------- layer 2 aggregate: no-max softmax, only last num_new nodes ----------------
__global__ void agg2_kernel(const int* __restrict__ edge_src, const int* __restrict__ offsets,
                            const float* __restrict__ as2, const float* __restrict__ ad2,
                            const float* __restrict__ hx2, const float* __restrict__ b2,
                            float* __restrict__ out, int N, int num_new) {
    __shared__ int   ssh[4][64];
    __shared__ float esh[4][64];
    int wid  = threadIdx.x >> 6;
    int w    = (blockIdx.x * blockDim.x + threadIdx.x) >> 6;
    int lane = threadIdx.x & 63;
    if (w >= num_new) return;
    int n = N - num_new + w;
    float adn = ad2[n];
    int beg = offsets[n], end = offsets[n + 1];

    float den = 0.f, acc = 0.f;
    for (int cb = beg; cb < end; cb += 64) {
        int j = cb + lane;
        bool valid = j < end;
        int s = valid ? edge_src[j] : 0;
        float e = 0.f;
        if (valid) {
            float v = as2[s] + adn;
            v = v > 0.f ? v : 0.2f * v;
            e = __expf(v);
            den += e;
        }
        ssh[wid][lane] = s;
        esh[wid][lane] = e;

        int cnt = min(64, end - cb);
#pragma unroll 4
        for (int jj = 0; jj < cnt; ++jj) {
            int   sj = ssh[wid][jj];
            float wj = esh[wid][jj];
            acc += wj * hx2[(size_t)sj * D2N + lane];
        }
    }
#pragma unroll
    for (int off = 32; off > 0; off >>= 1) den += __shfl_xor(den, off, 64);
    out[(size_t)w * D2N + lane] = acc / (den + 1e-16f) + b2[lane];
}

// ---------------- launch ----------------
extern "C" void kernel_launch(void* const* d_in, const int* in_sizes, int n_in,
                              void* d_out, int out_size, void* d_ws, size_t ws_size,
                              hipStream_t stream) {
    const float* x      = (const float*)d_in[0];
    const int*   src    = (const int*)d_in[1];
    const int*   dst    = (const int*)d_in[2];
    const float* W1     = (const float*)d_in[3];
    const float* attS1  = (const float*)d_in[4];
    const float* attD1  = (const float*)d_in[5];
    const float* b1     = (const float*)d_in[6];
    const float* W2     = (const float*)d_in[7];
    const float* attS2  = (const float*)d_in[8];
    const float* attD2  = (const float*)d_in[9];
    const float* b2     = (const float*)d_in[10];

    const int N = in_sizes[0] / F_IN;   // 50000
    const int E = in_sizes[1];          // 1000000
    const int num_new = out_size / D2N; // 10000
    const int ntiles = (N + SCAN_TILE - 1) / SCAN_TILE;   // 98
    const int ngemm  = (N + 63) / 64;                     // 782

    // workspace carve-up
    __half* hx1h = (__half*)d_ws;                        // N*128 halves
    float* x1  = (float*)(hx1h + (size_t)N * C1);        // N*128 f32
    float* hx2 = x1  + (size_t)N * C1;                   // N*64
    float* as1 = hx2 + (size_t)N * D2N;                  // N*4
    float* ad1 = as1 + (size_t)N * H1N;                  // N*4
    float* as2 = ad1 + (size_t)N * H1N;                  // N
    float* ad2 = as2 + N;                                // N
    int* counts    = (int*)(ad2 + N);                    // N
    int* offsets   = counts + N;                         // N+1
    int* tilesums  = offsets + N + 1;                    // 256
    int* tilebase  = tilesums + 256;                     // 256
    int* edge_src  = tilebase + 256;                     // E
    int* edge_rank = edge_src + E;                       // E

    float* out = (float*)d_out;

    hipLaunchKernelGGL(zero_ints, dim3(256), dim3(256), 0, stream, counts, N);
    hipLaunchKernelGGL(gemm1_count_kernel, dim3(ngemm + 1024), dim3(128), 0, stream,
                       x, W1, attS1, attD1, hx1h, as1, ad1, N,
                       dst, counts, edge_rank, E, ngemm);
    hipLaunchKernelGGL(scan_partial, dim3(ntiles), dim3(SCAN_T), 0, stream, counts, tilesums, N);
    hipLaunchKernelGGL(scan_tops, dim3(1), dim3(SCAN_T), 0, stream, tilesums, tilebase, ntiles);
    hipLaunchKernelGGL(scan_final, dim3(ntiles), dim3(SCAN_T), 0, stream,
                       counts, tilebase, offsets, N, E);
    hipLaunchKernelGGL(scatter_rank, dim3(2048), dim3(256), 0, stream,
                       src, dst, edge_rank, offsets, edge_src, E, N);
    hipLaunchKernelGGL(agg1_kernel, dim3((N + 3) / 4), dim3(256), 0, stream,
                       edge_src, offsets, as1, ad1, hx1h, b1, x1, N);
    hipLaunchKernelGGL(gemm2_kernel, dim3((N + 63) / 64), dim3(256), 0, stream,
                       x1, W2, attS2, attD2, hx2, as2, ad2, N);
    hipLaunchKernelGGL(agg2_kernel, dim3((num_new + 3) / 4), dim3(256), 0, stream,
                       edge_src, offsets, as2, ad2, hx2, b2, out, N, num_new);
}